// Round 8
// baseline (235.713 us; speedup 1.0000x reference)
//
#include <hip/hip_runtime.h>

typedef unsigned short u16;
typedef __bf16 bf16x8_v __attribute__((ext_vector_type(8)));
typedef float f32x4 __attribute__((ext_vector_type(4)));

// ---------- bf16 helpers ----------
__device__ __forceinline__ u16 f2bf(float f) {
    unsigned u = __float_as_uint(f);
    unsigned r = u + 0x7fffu + ((u >> 16) & 1u);   // RNE; inputs finite
    return (u16)(r >> 16);
}
__device__ __forceinline__ float bf2f(u16 h) {
    return __uint_as_float(((unsigned)h) << 16);
}

// async global->LDS, 16B per lane; lds dst = WAVE-UNIFORM base, HW adds lane*16
__device__ __forceinline__ void gll16(const u16* g, u16* l) {
    __builtin_amdgcn_global_load_lds(
        (const __attribute__((address_space(1))) void*)g,
        (__attribute__((address_space(3))) void*)l, 16, 0, 0);
}

#define EXP_SHIFT 12.0f   // fixed-shift softmax: e = exp(score - SHIFT)

// Srow lives in dead space of Sb: rows 0..3 of each batch, cols 1024..1535
// (row-block 0 only ever has cols <128 written/read by scores/pv).
__device__ __forceinline__ float* srow_ptr(u16* Sb, int b, int i) {
    return (float*)((char*)Sb + (size_t)b * 8388608 +
                    ((i >> 9) << 12) + 2048 + ((size_t)(i & 511) << 2));
}

// ---- prep: x->bf16, W->Wt3 transposed, zero Srow, zero O atomic region -----
// grid 8193 x 256.
__global__ __launch_bounds__(256) void k_prep(const float* __restrict__ x,
                                              const float* __restrict__ Wq,
                                              const float* __restrict__ Wk,
                                              const float* __restrict__ Wv,
                                              u16* __restrict__ xb,
                                              u16* __restrict__ Wt3,
                                              u16* __restrict__ Sb,
                                              float* __restrict__ O) {
    __shared__ float tile[32][33];
    const int bid = blockIdx.x, tid = threadIdx.x;
    if (bid < 4096) {                       // x fp32 -> bf16, 8 elem/thread
        int i = (bid * 256 + tid) * 8;
        float4 a = *(const float4*)(x + i);
        float4 bb = *(const float4*)(x + i + 4);
        union { int4 p; u16 h[8]; } o;
        o.h[0] = f2bf(a.x);  o.h[1] = f2bf(a.y);  o.h[2] = f2bf(a.z);  o.h[3] = f2bf(a.w);
        o.h[4] = f2bf(bb.x); o.h[5] = f2bf(bb.y); o.h[6] = f2bf(bb.z); o.h[7] = f2bf(bb.w);
        *(int4*)(xb + i) = o.p;
    } else if (bid < 7168) {                // W transpose x3 -> Wt3
        const int w = bid - 4096;
        const int z = w >> 10, rem = w & 1023;
        const int bx = rem & 31, by = rem >> 5;
        const float* W = (z == 0) ? Wq : (z == 1) ? Wk : Wv;
        u16* Wt = Wt3 + (size_t)z * 1024 * 1024;
        const int tx = tid & 31, ty = tid >> 5;
#pragma unroll
        for (int r = 0; r < 4; ++r)
            tile[ty + r * 8][tx] = W[(by * 32 + ty + r * 8) * 1024 + bx * 32 + tx];
        __syncthreads();
#pragma unroll
        for (int r = 0; r < 4; ++r)
            Wt[(bx * 32 + ty + r * 8) * 1024 + by * 32 + tx] =
                f2bf(tile[tx][ty + r * 8]);
    } else if (bid == 7168) {               // zero Srow dead-space (32 KB)
        const int chunk = tid >> 7;
        const int t = tid & 127;
        int4 z4 = {0, 0, 0, 0};
#pragma unroll
        for (int c = 0; c < 8; ++c) {
            const int cc = c * 2 + chunk;   // 0..15: b = cc>>2, r = cc&3
            char* p = (char*)Sb + (size_t)(cc >> 2) * 8388608 +
                      ((cc & 3) << 12) + 2048;
            *(int4*)(p + t * 16) = z4;
        }
    } else {                                // zero O rows [1024,2048) per b
        const int k = bid - 7169;           // 0..1023 (16 MB total)
        const int b = k >> 8;
        float* p = O + (size_t)b * 2097152 + 1048576 +
                   (size_t)(k & 255) * 4096;
        float4 z4 = {0.f, 0.f, 0.f, 0.f};
        ((float4*)p)[tid]       = z4;
        ((float4*)p)[tid + 256] = z4;
        ((float4*)p)[tid + 512] = z4;
        ((float4*)p)[tid + 768] = z4;
    }
}

// ---------------- GEMM core: NT, BK=64, XOR-swizzled LDS ----------------
// C[m][n] = sum_k A[m][k] * Bnt[n][k]. 4 waves (2x2), tile 128x128, BK=64.
// LDS chunk position p of row r holds global chunk p^(r&7).
__device__ __forceinline__ void gemm_core_nt(const u16* __restrict__ A,
                                             const u16* __restrict__ B,
                                             int lda, int ldb, int kLen,
                                             u16* smem, f32x4 acc[4][4]) {
    u16* As = smem;
    u16* Bs = smem + 128 * 64;
    const int tid = threadIdx.x;
    const int wave = tid >> 6;
    const int lane = tid & 63;
    const int rowA = tid >> 3;
    const int kcs  = (tid & 7) ^ (rowA & 7);
    const int row16 = lane & 15;
    const int quad = lane >> 4;
    const int sw = row16 & 7;
    const int wm = (wave >> 1) * 64;
    const int wn = (wave & 1) * 64;

#pragma unroll
    for (int i = 0; i < 4; ++i)
#pragma unroll
        for (int j = 0; j < 4; ++j) {
            f32x4 z = {0.f, 0.f, 0.f, 0.f};
            acc[i][j] = z;
        }

    const u16* Ag[4]; const u16* Bg[4];
    u16 *AsB[4], *BsB[4];
#pragma unroll
    for (int u = 0; u < 4; ++u) {
        Ag[u] = A + (size_t)(u * 32 + rowA) * lda + kcs * 8;
        Bg[u] = B + (size_t)(u * 32 + rowA) * ldb + kcs * 8;
        AsB[u] = As + (u * 256 + wave * 64) * 8;
        BsB[u] = Bs + (u * 256 + wave * 64) * 8;
    }

    const int ktiles = kLen >> 6;
    for (int kt = 0; kt < ktiles; ++kt) {
        __syncthreads();
#pragma unroll
        for (int u = 0; u < 4; ++u) gll16(Ag[u] + kt * 64, AsB[u]);
#pragma unroll
        for (int u = 0; u < 4; ++u) gll16(Bg[u] + kt * 64, BsB[u]);
        __syncthreads();
#pragma unroll
        for (int h = 0; h < 2; ++h) {
            bf16x8_v af[4], bfv[4];
            const int cp = (h * 4 + quad);
#pragma unroll
            for (int i = 0; i < 4; ++i)
                af[i] = *(const bf16x8_v*)(As + (wm + i * 16 + row16) * 64 +
                                           (cp ^ sw) * 8);
#pragma unroll
            for (int j = 0; j < 4; ++j)
                bfv[j] = *(const bf16x8_v*)(Bs + (wn + j * 16 + row16) * 64 +
                                            (cp ^ sw) * 8);
#pragma unroll
            for (int i = 0; i < 4; ++i)
#pragma unroll
                for (int j = 0; j < 4; ++j)
                    acc[i][j] = __builtin_amdgcn_mfma_f32_16x16x32_bf16(
                        af[i], bfv[j], acc[i][j], 0, 0, 0);
        }
    }
}

// Coalesced bf16 epilogue (row-major): wave 64x64 tile via 4 KB LDS slice.
__device__ __forceinline__ void epi_bf16(const f32x4 acc[4][4], u16* smem,
                                         u16* __restrict__ g, int ldg) {
    const int tid = threadIdx.x;
    const int wave = tid >> 6, lane = tid & 63;
    const int row16 = lane & 15, quad = lane >> 4;
    u16* Ts = smem + wave * 2048;
#pragma unroll
    for (int jh = 0; jh < 2; ++jh) {
#pragma unroll
        for (int i = 0; i < 4; ++i)
#pragma unroll
            for (int jj = 0; jj < 2; ++jj) {
                const int j = jh * 2 + jj;
#pragma unroll
                for (int r = 0; r < 4; ++r)
                    Ts[(i * 16 + quad * 4 + r) * 32 + jj * 16 + row16] =
                        f2bf(acc[i][j][r]);
            }
#pragma unroll
        for (int s = 0; s < 4; ++s) {
            const int row = s * 16 + (lane >> 2);
            int4 val = *(const int4*)(Ts + row * 32 + (lane & 3) * 8);
            *(int4*)(g + (size_t)row * ldg + jh * 32 + (lane & 3) * 8) = val;
        }
    }
}

// V-transposed epilogue: wave 64x64 -> Vt[e][s], 16B runs along s.
__device__ __forceinline__ void epi_vt(const f32x4 acc[4][4], u16* smem,
                                       u16* __restrict__ Vt, int m0w, int n0w) {
    const int tid = threadIdx.x;
    const int wave = tid >> 6, lane = tid & 63;
    const int row16 = lane & 15, quad = lane >> 4;
    const int b = m0w >> 11;
    const int sBase = m0w & 2047;
    u16* Ts = smem + wave * 4608;            // 32 x 72 u16
#pragma unroll
    for (int p = 0; p < 2; ++p) {
#pragma unroll
        for (int i = 0; i < 4; ++i)
#pragma unroll
            for (int jj = 0; jj < 2; ++jj) {
                const int j = p * 2 + jj;
                union { unsigned long long d; u16 h[4]; } o;
#pragma unroll
                for (int r = 0; r < 4; ++r) o.h[r] = f2bf(acc[i][j][r]);
                *(unsigned long long*)(Ts + (jj * 16 + row16) * 72 +
                                       i * 16 + quad * 4) = o.d;
            }
#pragma unroll
        for (int rr = 0; rr < 4; ++rr) {
            const int ln = rr * 8 + (lane >> 3);
            const int ck = lane & 7;
            int4 val = *(const int4*)(Ts + ln * 72 + ck * 8);
            const int n = n0w + p * 32 + ln;
            *(int4*)(Vt + ((size_t)b * 1024 + n) * 2048 + sBase + ck * 8) = val;
        }
    }
}

// ---------------- Q,K projection (r0 structure): grid (16, 64) --------------
__global__ __launch_bounds__(256, 3) void k_projqk(const u16* __restrict__ X,
                                                   const u16* __restrict__ Wt3,
                                                   u16* __restrict__ Qb,
                                                   u16* __restrict__ Kb) {
    __shared__ u16 smem[16384];              // 32 KB
    const int n0g = blockIdx.x * 128, m0 = blockIdx.y * 128;
    f32x4 acc[4][4];
    gemm_core_nt(X + (size_t)m0 * 1024, Wt3 + (size_t)n0g * 1024, 1024, 1024, 1024,
                 smem, acc);
    const int tid = threadIdx.x, wave = tid >> 6;
    const int wm = (wave >> 1) * 64, wn = (wave & 1) * 64;
    __syncthreads();
    u16* Y = (n0g < 1024) ? Qb : Kb;
    const int n0 = n0g & 1023;
    epi_bf16(acc, smem, Y + (size_t)(m0 + wm) * 1024 + n0 + wn, 1024);
}

// ---------------- V projection: grid (8, 64) --------------------------------
__global__ __launch_bounds__(256, 3) void k_projv(const u16* __restrict__ X,
                                                  const u16* __restrict__ Wt3,
                                                  u16* __restrict__ Vt) {
    __shared__ u16 smem[18432];              // 36 KB (epi_vt needs 4x4608)
    const int nv = blockIdx.x, m0 = blockIdx.y * 128;
    f32x4 acc[4][4];
    gemm_core_nt(X + (size_t)m0 * 1024,
                 Wt3 + (size_t)(2048 + nv * 128) * 1024, 1024, 1024, 1024,
                 smem, acc);
    const int tid = threadIdx.x, wave = tid >> 6;
    const int wm = (wave >> 1) * 64, wn = (wave & 1) * 64;
    __syncthreads();
    epi_vt(acc, smem, Vt, m0 + wm, nv * 128 + wn);
}

// Scores + fused unnormalized exp; lower-triangular tiles; grid 544 (1-D).
// XCD-grouping: 68 consecutive triangle indices per XCD.
__global__ __launch_bounds__(256, 4) void k_gemm_scores(const u16* __restrict__ Q,
                                                        const u16* __restrict__ Kb,
                                                        u16* __restrict__ Sb) {
    __shared__ u16 smem[16384];
    const int lin = blockIdx.x;                       // 0..543
    const int lin2 = (lin & 7) * 68 + (lin >> 3);     // bijective (544 = 8*68)
    int t = lin2 % 136, b = lin2 / 136;
    int mt = 0;
    while ((mt + 1) * (mt + 2) / 2 <= t) ++mt;
    int nt = t - mt * (mt + 1) / 2;
    const u16* Qp = Q + (size_t)b * 2048 * 1024 + (size_t)mt * 128 * 1024;
    const u16* Kp = Kb + (size_t)b * 2048 * 1024 + (size_t)nt * 128 * 1024;
    u16* Sp = Sb + (size_t)b * 2048 * 2048;
    f32x4 acc[4][4];
    gemm_core_nt(Qp, Kp, 1024, 1024, 1024, smem, acc);
    const int tid = threadIdx.x, wave = tid >> 6, lane = tid & 63;
    const int wm = (wave >> 1) * 64, wn = (wave & 1) * 64;
    const int row16 = lane & 15, quad = lane >> 4;
    const int mBase = mt * 128 + wm;
    const int nBase = nt * 128 + wn;
    u16* Ts = smem + wave * 2048;
    float rs[4][4];
#pragma unroll
    for (int i = 0; i < 4; ++i)
#pragma unroll
        for (int r = 0; r < 4; ++r) rs[i][r] = 0.f;

    __syncthreads();
#pragma unroll
    for (int jh = 0; jh < 2; ++jh) {
#pragma unroll
        for (int i = 0; i < 4; ++i)
#pragma unroll
            for (int jj = 0; jj < 2; ++jj) {
                const int j = jh * 2 + jj;
                const int n = nBase + jh * 32 + jj * 16 + row16;
#pragma unroll
                for (int r = 0; r < 4; ++r) {
                    const int m = mBase + i * 16 + quad * 4 + r;
                    float e = 0.f;
                    if (n <= m)
                        e = __expf(acc[i][j][r] * 0.03125f - EXP_SHIFT);
                    rs[i][r] += e;
                    Ts[(i * 16 + quad * 4 + r) * 32 + jj * 16 + row16] = f2bf(e);
                }
            }
#pragma unroll
        for (int s = 0; s < 4; ++s) {
            const int row = s * 16 + (lane >> 2);
            int4 val = *(const int4*)(Ts + row * 32 + (lane & 3) * 8);
            *(int4*)(Sp + (size_t)(mBase + row) * 2048 +
                     nBase + jh * 32 + (lane & 3) * 8) = val;
        }
    }
#pragma unroll
    for (int i = 0; i < 4; ++i)
#pragma unroll
        for (int r = 0; r < 4; ++r) {
            float s = rs[i][r];
#pragma unroll
            for (int off = 1; off < 16; off <<= 1) s += __shfl_xor(s, off);
            if (row16 == 0)
                atomicAdd(srow_ptr((u16*)Sb, b, mBase + i * 16 + quad * 4 + r), s);
        }
}

// PV v3: uniform split-K, balanced, scheduler-assumption-free. grid 768.
// Per (b,nt): 24 K-chunks cover the triangle row-block set: mt<=7 one chunk
// (kLen=(mt+1)*128, plain STORE), mt>=8 two chunks (c0: K=1024, c1:
// K=(mt-7)*128, both unsafeAtomicAdd into O rows pre-zeroed by prep).
// Max chunk K = 1024 -> makespan bounded regardless of scheduler.
// Task table t=0..23 ordered by K desc:
//   t<8: (mt=15-t, c0, K=1024); t=8: (mt=7, c0, K=1024); t=9: (mt=15, c1,
//   K=1024); t>=10: pairs (mt=6-q, c0) / (mt=14-q, c1), q=(t-10)>>1.
// Class/tier layout: bid = ((tt*4+b)*8 + nt)*8 + c; t(c,tt): tt0 -> c,
// tt1 -> 8+c, tt2 -> 22-(c&6)+(c&1). Each class-c triple of K sums to
// exactly 2176 (1024+1024+128, +896+256, +768+384, +640+512) -> per-CU
// work constant under breadth-first wrap; all 8 nt of a (b,t) group share
// bid%8 -> same XCD -> P-tile L2-shared.
__global__ __launch_bounds__(256, 4) void k_gemm_pv(u16* __restrict__ P,
                                                    const u16* __restrict__ Vt,
                                                    float* __restrict__ O) {
    __shared__ u16 smem[16384];
    const int bid = blockIdx.x;              // 0..767
    const int c = bid & 7;
    const int slot = bid >> 3;               // 0..95
    const int nt = slot & 7;
    const int j = slot >> 3;                 // 0..11
    const int b = j & 3;
    const int tt = j >> 2;                   // 0..2
    const int t = (tt == 0) ? c : (tt == 1) ? (8 + c) : (22 - (c & 6) + (c & 1));
    int mt, ch;
    if (t < 8)       { mt = 15 - t; ch = 0; }
    else if (t == 8) { mt = 7;      ch = 0; }
    else if (t == 9) { mt = 15;     ch = 1; }
    else {
        const int q = (t - 10) >> 1;
        if ((t - 10) & 1) { mt = 14 - q; ch = 1; }
        else              { mt = 6 - q;  ch = 0; }
    }
    const int k0 = ch << 10;
    const int kLen = ch ? (mt - 7) * 128 : ((mt >= 7) ? 1024 : (mt + 1) * 128);
    const bool full = (ch == 0) && (mt <= 7);

    const u16* Pp = P + (size_t)b * 2048 * 2048 + (size_t)mt * 128 * 2048 + k0;
    const u16* Vp = Vt + (size_t)b * 1024 * 2048 + (size_t)nt * 128 * 2048 + k0;
    f32x4 acc[4][4];
    gemm_core_nt(Pp, Vp, 2048, 2048, kLen, smem, acc);
    float* Op = O + (size_t)b * 2048 * 1024;
    const int tid = threadIdx.x, wave = tid >> 6, lane = tid & 63;
    const int wm = (wave >> 1) * 64, wn = (wave & 1) * 64;
    const int row16 = lane & 15, quad = lane >> 4;
    float inv[4][4];
#pragma unroll
    for (int i = 0; i < 4; ++i)
#pragma unroll
        for (int r = 0; r < 4; ++r)
            inv[i][r] = 1.0f / *srow_ptr(P, b, mt * 128 + wm + i * 16 + quad * 4 + r);
    if (full) {
#pragma unroll
        for (int i = 0; i < 4; ++i)
#pragma unroll
            for (int j2 = 0; j2 < 4; ++j2) {
                int m = mt * 128 + wm + i * 16 + quad * 4;
                int n = nt * 128 + wn + j2 * 16 + row16;
#pragma unroll
                for (int r = 0; r < 4; ++r)
                    Op[(size_t)(m + r) * 1024 + n] = acc[i][j2][r] * inv[i][r];
            }
    } else {
#pragma unroll
        for (int i = 0; i < 4; ++i)
#pragma unroll
            for (int j2 = 0; j2 < 4; ++j2) {
                int m = mt * 128 + wm + i * 16 + quad * 4;
                int n = nt * 128 + wn + j2 * 16 + row16;
#pragma unroll
                for (int r = 0; r < 4; ++r)
                    unsafeAtomicAdd(&Op[(size_t)(m + r) * 1024 + n],
                                    acc[i][j2][r] * inv[i][r]);
            }
    }
}

// ---------------- launcher ----------------
extern "C" void kernel_launch(void* const* d_in, const int* in_sizes, int n_in,
                              void* d_out, int out_size, void* d_ws, size_t ws_size,
                              hipStream_t stream) {
    const float* x  = (const float*)d_in[0];
    const float* Wq = (const float*)d_in[1];
    const float* Wk = (const float*)d_in[2];
    const float* Wv = (const float*)d_in[3];
    float* out = (float*)d_out;
    char* ws = (char*)d_ws;

    u16* xb  = (u16*)(ws);                          // 16 MB: x bf16 [8192,1024]
    u16* Wt3 = (u16*)(ws + (16u << 20));            //  6 MB
    u16* Qb  = (u16*)(ws + (22u << 20));            // 16 MB
    u16* Kb  = (u16*)(ws + (38u << 20));            // 16 MB
    u16* Vt  = (u16*)(ws + (54u << 20));            // 16 MB: V^T [B,1024,2048]
    u16* Sb  = (u16*)(ws + (70u << 20));            // 32 MB: P' (+Srow dead space)

    k_prep<<<8193, 256, 0, stream>>>(x, Wq, Wk, Wv, xb, Wt3, Sb, out);
    k_projqk<<<dim3(16, 64), 256, 0, stream>>>(xb, Wt3, Qb, Kb);
    k_projv<<<dim3(8, 64), 256, 0, stream>>>(xb, Wt3, Vt);
    k_gemm_scores<<<544, 256, 0, stream>>>(Qb, Kb, Sb);
    k_gemm_pv<<<768, 256, 0, stream>>>(Sb, Vt, out);
}

// Round 10
// 217.786 us; speedup vs baseline: 1.0823x; 1.0823x over previous
//
#include <hip/hip_runtime.h>

typedef unsigned short u16;
typedef __bf16 bf16x8_v __attribute__((ext_vector_type(8)));
typedef float f32x4 __attribute__((ext_vector_type(4)));

// ---------- bf16 helpers ----------
__device__ __forceinline__ u16 f2bf(float f) {
    unsigned u = __float_as_uint(f);
    unsigned r = u + 0x7fffu + ((u >> 16) & 1u);   // RNE; inputs finite
    return (u16)(r >> 16);
}
__device__ __forceinline__ float bf2f(u16 h) {
    return __uint_as_float(((unsigned)h) << 16);
}

// async global->LDS, 16B per lane; lds dst = WAVE-UNIFORM base, HW adds lane*16
__device__ __forceinline__ void gll16(const u16* g, u16* l) {
    __builtin_amdgcn_global_load_lds(
        (const __attribute__((address_space(1))) void*)g,
        (__attribute__((address_space(3))) void*)l, 16, 0, 0);
}

#define EXP_SHIFT 12.0f   // fixed-shift softmax: e = exp(score - SHIFT)

// Srow lives in dead space of Sb: rows 0..3 of each batch, cols 1024..1535
// (row-block 0 only ever has cols <128 written/read by scores/pv).
__device__ __forceinline__ float* srow_ptr(u16* Sb, int b, int i) {
    return (float*)((char*)Sb + (size_t)b * 8388608 +
                    ((i >> 9) << 12) + 2048 + ((size_t)(i & 511) << 2));
}

// ---------------- prep: x->bf16, W->Wt3 bf16 transposed, zero Srow ----------
// grid 7169 x 256.
__global__ __launch_bounds__(256) void k_prep(const float* __restrict__ x,
                                              const float* __restrict__ Wq,
                                              const float* __restrict__ Wk,
                                              const float* __restrict__ Wv,
                                              u16* __restrict__ xb,
                                              u16* __restrict__ Wt3,
                                              u16* __restrict__ Sb) {
    __shared__ float tile[32][33];
    const int bid = blockIdx.x, tid = threadIdx.x;
    if (bid < 4096) {                       // x fp32 -> bf16, 8 elem/thread
        int i = (bid * 256 + tid) * 8;
        float4 a = *(const float4*)(x + i);
        float4 bb = *(const float4*)(x + i + 4);
        union { int4 p; u16 h[8]; } o;
        o.h[0] = f2bf(a.x);  o.h[1] = f2bf(a.y);  o.h[2] = f2bf(a.z);  o.h[3] = f2bf(a.w);
        o.h[4] = f2bf(bb.x); o.h[5] = f2bf(bb.y); o.h[6] = f2bf(bb.z); o.h[7] = f2bf(bb.w);
        *(int4*)(xb + i) = o.p;
    } else if (bid < 7168) {                // W transpose x3 -> Wt3
        const int w = bid - 4096;
        const int z = w >> 10, rem = w & 1023;
        const int bx = rem & 31, by = rem >> 5;
        const float* W = (z == 0) ? Wq : (z == 1) ? Wk : Wv;
        u16* Wt = Wt3 + (size_t)z * 1024 * 1024;
        const int tx = tid & 31, ty = tid >> 5;
#pragma unroll
        for (int r = 0; r < 4; ++r)
            tile[ty + r * 8][tx] = W[(by * 32 + ty + r * 8) * 1024 + bx * 32 + tx];
        __syncthreads();
#pragma unroll
        for (int r = 0; r < 4; ++r)
            Wt[(bx * 32 + ty + r * 8) * 1024 + by * 32 + tx] =
                f2bf(tile[tx][ty + r * 8]);
    } else {                                // zero Srow dead-space (32 KB)
        const int chunk = tid >> 7;
        const int t = tid & 127;
#pragma unroll
        for (int c = 0; c < 8; ++c) {
            const int cc = c * 2 + chunk;   // 0..15: b = cc>>2, r = cc&3
            char* p = (char*)Sb + (size_t)(cc >> 2) * 8388608 +
                      ((cc & 3) << 12) + 2048;
            int4 z4 = {0, 0, 0, 0};
            *(int4*)(p + t * 16) = z4;
        }
    }
}

// ---------------- GEMM core: NT, BK=64, XOR-swizzled LDS (no prefetch) ------
// C[m][n] = sum_k A[m][k] * Bnt[n][k]. 4 waves (2x2), tile 128x128, BK=64.
// LDS chunk position p of row r holds global chunk p^(r&7). Used by proj
// (L2-warm operands -> at its structure's ceiling, ~926 TF measured).
__device__ __forceinline__ void gemm_core_nt(const u16* __restrict__ A,
                                             const u16* __restrict__ B,
                                             int lda, int ldb, int kLen,
                                             u16* smem, f32x4 acc[4][4]) {
    u16* As = smem;
    u16* Bs = smem + 128 * 64;
    const int tid = threadIdx.x;
    const int wave = tid >> 6;
    const int lane = tid & 63;
    const int rowA = tid >> 3;
    const int kcs  = (tid & 7) ^ (rowA & 7);
    const int row16 = lane & 15;
    const int quad = lane >> 4;
    const int sw = row16 & 7;
    const int wm = (wave >> 1) * 64;
    const int wn = (wave & 1) * 64;

#pragma unroll
    for (int i = 0; i < 4; ++i)
#pragma unroll
        for (int j = 0; j < 4; ++j) {
            f32x4 z = {0.f, 0.f, 0.f, 0.f};
            acc[i][j] = z;
        }

    const u16* Ag[4]; const u16* Bg[4];
    u16 *AsB[4], *BsB[4];
#pragma unroll
    for (int u = 0; u < 4; ++u) {
        Ag[u] = A + (size_t)(u * 32 + rowA) * lda + kcs * 8;
        Bg[u] = B + (size_t)(u * 32 + rowA) * ldb + kcs * 8;
        AsB[u] = As + (u * 256 + wave * 64) * 8;
        BsB[u] = Bs + (u * 256 + wave * 64) * 8;
    }

    const int ktiles = kLen >> 6;
    for (int kt = 0; kt < ktiles; ++kt) {
        __syncthreads();
#pragma unroll
        for (int u = 0; u < 4; ++u) gll16(Ag[u] + kt * 64, AsB[u]);
#pragma unroll
        for (int u = 0; u < 4; ++u) gll16(Bg[u] + kt * 64, BsB[u]);
        __syncthreads();
#pragma unroll
        for (int h = 0; h < 2; ++h) {
            bf16x8_v af[4], bfv[4];
            const int cp = (h * 4 + quad);
#pragma unroll
            for (int i = 0; i < 4; ++i)
                af[i] = *(const bf16x8_v*)(As + (wm + i * 16 + row16) * 64 +
                                           (cp ^ sw) * 8);
#pragma unroll
            for (int j = 0; j < 4; ++j)
                bfv[j] = *(const bf16x8_v*)(Bs + (wn + j * 16 + row16) * 64 +
                                            (cp ^ sw) * 8);
#pragma unroll
            for (int i = 0; i < 4; ++i)
#pragma unroll
                for (int j = 0; j < 4; ++j)
                    acc[i][j] = __builtin_amdgcn_mfma_f32_16x16x32_bf16(
                        af[i], bfv[j], acc[i][j], 0, 0, 0);
        }
    }
}

// ------------ GEMM core, double-buffered (T3-minimum 2-phase) ---------------
// Same tile/swizzle as gemm_core_nt, but K-tile t+1 is staged into the
// alternate 32 KB buffer BEFORE computing tile t, so its HBM/L3 latency
// (~600-900 cyc for the L2-cold Q/K/P/V panels of scores/pv) overlaps the
// compute phase instead of being serialized at the barrier drain. One
// __syncthreads per K-step (its vmcnt0+lgkmcnt0 drain retires the prefetch
// AND all ds_reads of the buffer overwritten next step -> WAR-safe).
// LDS: 64 KB (buf pair x {A 8192, B 8192} u16) -> 2 blocks/CU.
__device__ __forceinline__ void gemm_core_nt_db(const u16* __restrict__ A,
                                                const u16* __restrict__ B,
                                                int lda, int ldb, int kLen,
                                                u16* smem, f32x4 acc[4][4]) {
    const int tid = threadIdx.x;
    const int wave = tid >> 6;
    const int lane = tid & 63;
    const int rowA = tid >> 3;
    const int kcs  = (tid & 7) ^ (rowA & 7);
    const int row16 = lane & 15;
    const int quad = lane >> 4;
    const int sw = row16 & 7;
    const int wm = (wave >> 1) * 64;
    const int wn = (wave & 1) * 64;

#pragma unroll
    for (int i = 0; i < 4; ++i)
#pragma unroll
        for (int j = 0; j < 4; ++j) {
            f32x4 z = {0.f, 0.f, 0.f, 0.f};
            acc[i][j] = z;
        }

    const u16* Ag[4]; const u16* Bg[4];
    int AsO[4], BsO[4];                      // offsets within a buffer pair
#pragma unroll
    for (int u = 0; u < 4; ++u) {
        Ag[u] = A + (size_t)(u * 32 + rowA) * lda + kcs * 8;
        Bg[u] = B + (size_t)(u * 32 + rowA) * ldb + kcs * 8;
        AsO[u] = (u * 256 + wave * 64) * 8;
        BsO[u] = AsO[u] + 8192;
    }

#define STG_DB(kt_, base_) do { \
    _Pragma("unroll") for (int u = 0; u < 4; ++u) { \
        gll16(Ag[u] + (kt_) * 64, smem + (base_) + AsO[u]); \
        gll16(Bg[u] + (kt_) * 64, smem + (base_) + BsO[u]); } } while (0)

    const int ktiles = kLen >> 6;
    STG_DB(0, 0);
    __syncthreads();                         // tile 0 landed
    for (int kt = 0; kt < ktiles; ++kt) {
        const int cb = (kt & 1) * 16384;
        if (kt + 1 < ktiles) STG_DB(kt + 1, 16384 - cb);   // prefetch t+1
        const u16* As = smem + cb;
        const u16* Bs = smem + cb + 8192;
#pragma unroll
        for (int h = 0; h < 2; ++h) {
            bf16x8_v af[4], bfv[4];
            const int cp = (h * 4 + quad);
#pragma unroll
            for (int i = 0; i < 4; ++i)
                af[i] = *(const bf16x8_v*)(As + (wm + i * 16 + row16) * 64 +
                                           (cp ^ sw) * 8);
#pragma unroll
            for (int j = 0; j < 4; ++j)
                bfv[j] = *(const bf16x8_v*)(Bs + (wn + j * 16 + row16) * 64 +
                                            (cp ^ sw) * 8);
#pragma unroll
            for (int i = 0; i < 4; ++i)
#pragma unroll
                for (int j = 0; j < 4; ++j)
                    acc[i][j] = __builtin_amdgcn_mfma_f32_16x16x32_bf16(
                        af[i], bfv[j], acc[i][j], 0, 0, 0);
        }
        __syncthreads();                     // prefetch landed; reads retired
    }
#undef STG_DB
}

// Coalesced bf16 epilogue (row-major): wave 64x64 tile via 4 KB LDS slice.
__device__ __forceinline__ void epi_bf16(const f32x4 acc[4][4], u16* smem,
                                         u16* __restrict__ g, int ldg) {
    const int tid = threadIdx.x;
    const int wave = tid >> 6, lane = tid & 63;
    const int row16 = lane & 15, quad = lane >> 4;
    u16* Ts = smem + wave * 2048;
#pragma unroll
    for (int jh = 0; jh < 2; ++jh) {
#pragma unroll
        for (int i = 0; i < 4; ++i)
#pragma unroll
            for (int jj = 0; jj < 2; ++jj) {
                const int j = jh * 2 + jj;
#pragma unroll
                for (int r = 0; r < 4; ++r)
                    Ts[(i * 16 + quad * 4 + r) * 32 + jj * 16 + row16] =
                        f2bf(acc[i][j][r]);
            }
#pragma unroll
        for (int s = 0; s < 4; ++s) {
            const int row = s * 16 + (lane >> 2);
            int4 val = *(const int4*)(Ts + row * 32 + (lane & 3) * 8);
            *(int4*)(g + (size_t)row * ldg + jh * 32 + (lane & 3) * 8) = val;
        }
    }
}

// V-transposed epilogue: wave 64x64 -> Vt[e][s], 16B runs along s.
__device__ __forceinline__ void epi_vt(const f32x4 acc[4][4], u16* smem,
                                       u16* __restrict__ Vt, int m0w, int n0w) {
    const int tid = threadIdx.x;
    const int wave = tid >> 6, lane = tid & 63;
    const int row16 = lane & 15, quad = lane >> 4;
    const int b = m0w >> 11;
    const int sBase = m0w & 2047;
    u16* Ts = smem + wave * 4608;            // 32 x 72 u16
#pragma unroll
    for (int p = 0; p < 2; ++p) {
#pragma unroll
        for (int i = 0; i < 4; ++i)
#pragma unroll
            for (int jj = 0; jj < 2; ++jj) {
                const int j = p * 2 + jj;
                union { unsigned long long d; u16 h[4]; } o;
#pragma unroll
                for (int r = 0; r < 4; ++r) o.h[r] = f2bf(acc[i][j][r]);
                *(unsigned long long*)(Ts + (jj * 16 + row16) * 72 +
                                       i * 16 + quad * 4) = o.d;
            }
#pragma unroll
        for (int rr = 0; rr < 4; ++rr) {
            const int ln = rr * 8 + (lane >> 3);
            const int ck = lane & 7;
            int4 val = *(const int4*)(Ts + ln * 72 + ck * 8);
            const int n = n0w + p * 32 + ln;
            *(int4*)(Vt + ((size_t)b * 1024 + n) * 2048 + sBase + ck * 8) = val;
        }
    }
}

// ---------------- fused QKV projection (r0 structure, measured ~926 TF) -----
__global__ __launch_bounds__(256, 3) void k_gemm_proj(const u16* __restrict__ X,
                                                      const u16* __restrict__ Wt3,
                                                      u16* __restrict__ Qb,
                                                      u16* __restrict__ Kb,
                                                      u16* __restrict__ Vt) {
    __shared__ u16 smem[18432];              // 36 KB
    const int n0g = blockIdx.x * 128, m0 = blockIdx.y * 128;
    f32x4 acc[4][4];
    gemm_core_nt(X + (size_t)m0 * 1024, Wt3 + (size_t)n0g * 1024, 1024, 1024, 1024,
                 smem, acc);
    const int tid = threadIdx.x, wave = tid >> 6;
    const int wm = (wave >> 1) * 64, wn = (wave & 1) * 64;
    __syncthreads();
    if (n0g < 2048) {
        u16* Y = (n0g < 1024) ? Qb : Kb;
        const int n0 = n0g & 1023;
        epi_bf16(acc, smem, Y + (size_t)(m0 + wm) * 1024 + n0 + wn, 1024);
    } else {
        epi_vt(acc, smem, Vt, m0 + wm, (n0g - 2048) + wn);
    }
}

// Scores + fused unnormalized exp; lower-triangular tiles; grid 544 (1-D).
// Double-buffered core (64 KB LDS, 2 blocks/CU). XCD-grouping: 68
// consecutive triangle indices per XCD; consecutive t share the Q-panel.
__global__ __launch_bounds__(256, 2) void k_gemm_scores(const u16* __restrict__ Q,
                                                        const u16* __restrict__ Kb,
                                                        u16* __restrict__ Sb) {
    __shared__ u16 smem[32768];              // 64 KB (dbuf)
    const int lin = blockIdx.x;                       // 0..543
    const int lin2 = (lin & 7) * 68 + (lin >> 3);     // bijective (544 = 8*68)
    int t = lin2 % 136, b = lin2 / 136;
    int mt = 0;
    while ((mt + 1) * (mt + 2) / 2 <= t) ++mt;
    int nt = t - mt * (mt + 1) / 2;
    const u16* Qp = Q + (size_t)b * 2048 * 1024 + (size_t)mt * 128 * 1024;
    const u16* Kp = Kb + (size_t)b * 2048 * 1024 + (size_t)nt * 128 * 1024;
    u16* Sp = Sb + (size_t)b * 2048 * 2048;
    f32x4 acc[4][4];
    gemm_core_nt_db(Qp, Kp, 1024, 1024, 1024, smem, acc);
    const int tid = threadIdx.x, wave = tid >> 6, lane = tid & 63;
    const int wm = (wave >> 1) * 64, wn = (wave & 1) * 64;
    const int row16 = lane & 15, quad = lane >> 4;
    const int mBase = mt * 128 + wm;
    const int nBase = nt * 128 + wn;
    u16* Ts = smem + wave * 2048;
    float rs[4][4];
#pragma unroll
    for (int i = 0; i < 4; ++i)
#pragma unroll
        for (int r = 0; r < 4; ++r) rs[i][r] = 0.f;

    __syncthreads();
#pragma unroll
    for (int jh = 0; jh < 2; ++jh) {
#pragma unroll
        for (int i = 0; i < 4; ++i)
#pragma unroll
            for (int jj = 0; jj < 2; ++jj) {
                const int j = jh * 2 + jj;
                const int n = nBase + jh * 32 + jj * 16 + row16;
#pragma unroll
                for (int r = 0; r < 4; ++r) {
                    const int m = mBase + i * 16 + quad * 4 + r;
                    float e = 0.f;
                    if (n <= m)
                        e = __expf(acc[i][j][r] * 0.03125f - EXP_SHIFT);
                    rs[i][r] += e;
                    Ts[(i * 16 + quad * 4 + r) * 32 + jj * 16 + row16] = f2bf(e);
                }
            }
#pragma unroll
        for (int s = 0; s < 4; ++s) {
            const int row = s * 16 + (lane >> 2);
            int4 val = *(const int4*)(Ts + row * 32 + (lane & 3) * 8);
            *(int4*)(Sp + (size_t)(mBase + row) * 2048 +
                     nBase + jh * 32 + (lane & 3) * 8) = val;
        }
    }
#pragma unroll
    for (int i = 0; i < 4; ++i)
#pragma unroll
        for (int r = 0; r < 4; ++r) {
            float s = rs[i][r];
#pragma unroll
            for (int off = 1; off < 16; off <<= 1) s += __shfl_xor(s, off);
            if (row16 == 0)
                atomicAdd(srow_ptr((u16*)Sb, b, mBase + i * 16 + quad * 4 + r), s);
        }
}

// PV: O = (1/Srow) * P'.V; k-extent (mt+1)*128. grid 512 (1-D), dbuf core,
// 2 blocks/CU (exactly one round). Decode: lin = h*256 + z, z = b*64 +
// nt*8 + mtp; mt = h ? mtp : 15-mtp. Slots z and z+256 co-reside under
// 2/CU wrap: K sums to 17*128 = 2176 constant per CU; pair shares (b,nt)
// -> same Vt panel in L2. Long half first (LPT fallback). No atomics.
__global__ __launch_bounds__(256, 2) void k_gemm_pv(u16* __restrict__ P,
                                                    const u16* __restrict__ Vt,
                                                    float* __restrict__ O) {
    __shared__ u16 smem[32768];              // 64 KB (dbuf)
    const int lin = blockIdx.x;              // 0..511
    const int h = lin >> 8;                  // 0: long half, 1: short half
    const int z = lin & 255;
    const int b = z >> 6;
    const int nt = (z >> 3) & 7;
    const int mtp = z & 7;
    const int mt = h ? mtp : (15 - mtp);
    const u16* Pp = P + (size_t)b * 2048 * 2048 + (size_t)mt * 128 * 2048;
    const u16* Vp = Vt + (size_t)b * 1024 * 2048 + (size_t)nt * 128 * 2048;
    f32x4 acc[4][4];
    gemm_core_nt_db(Pp, Vp, 2048, 2048, (mt + 1) * 128, smem, acc);
    float* Op = O + (size_t)b * 2048 * 1024;
    const int tid = threadIdx.x, wave = tid >> 6, lane = tid & 63;
    const int wm = (wave >> 1) * 64, wn = (wave & 1) * 64;
    const int row16 = lane & 15, quad = lane >> 4;
    float inv[4][4];
#pragma unroll
    for (int i = 0; i < 4; ++i)
#pragma unroll
        for (int r = 0; r < 4; ++r)
            inv[i][r] = 1.0f / *srow_ptr(P, b, mt * 128 + wm + i * 16 + quad * 4 + r);
#pragma unroll
    for (int i = 0; i < 4; ++i)
#pragma unroll
        for (int j = 0; j < 4; ++j) {
            int m = mt * 128 + wm + i * 16 + quad * 4;
            int n = nt * 128 + wn + j * 16 + row16;
#pragma unroll
            for (int r = 0; r < 4; ++r)
                Op[(size_t)(m + r) * 1024 + n] = acc[i][j][r] * inv[i][r];
        }
}

// ---------------- launcher ----------------
extern "C" void kernel_launch(void* const* d_in, const int* in_sizes, int n_in,
                              void* d_out, int out_size, void* d_ws, size_t ws_size,
                              hipStream_t stream) {
    const float* x  = (const float*)d_in[0];
    const float* Wq = (const float*)d_in[1];
    const float* Wk = (const float*)d_in[2];
    const float* Wv = (const float*)d_in[3];
    float* out = (float*)d_out;
    char* ws = (char*)d_ws;

    u16* xb  = (u16*)(ws);                          // 16 MB: x bf16 [8192,1024]
    u16* Wt3 = (u16*)(ws + (16u << 20));            //  6 MB
    u16* Qb  = (u16*)(ws + (22u << 20));            // 16 MB
    u16* Kb  = (u16*)(ws + (38u << 20));            // 16 MB
    u16* Vt  = (u16*)(ws + (54u << 20));            // 16 MB: V^T [B,1024,2048]
    u16* Sb  = (u16*)(ws + (70u << 20));            // 32 MB: P' (+Srow dead space)

    k_prep<<<7169, 256, 0, stream>>>(x, Wq, Wk, Wv, xb, Wt3, Sb);
    k_gemm_proj<<<dim3(24, 64), 256, 0, stream>>>(xb, Wt3, Qb, Kb, Vt);
    k_gemm_scores<<<544, 256, 0, stream>>>(Qb, Kb, Sb);
    k_gemm_pv<<<512, 256, 0, stream>>>(Sb, Vt, out);
}